// Round 1
// baseline (15604.999 us; speedup 1.0000x reference)
//
#include <hip/hip_runtime.h>
#include <math.h>

// Problem constants
constexpr int kS = 512, kH = 768, kNH = 12, kDH = 64, kF = 3072, kL = 12;
constexpr int kN = 50000, kE = 800000, kGH = 128;

#define CDIV(a,b) (((a)+(b)-1)/(b))

// ---------------- generic fill ----------------
__global__ void fill_kernel(float* p, float v, long n) {
    long i = blockIdx.x * (long)blockDim.x + threadIdx.x;
    if (i < n) p[i] = v;
}

// ---------------- embeddings + LN ----------------
__global__ void embed_ln_kernel(const int* ids, const int* tt,
                                const float* we, const float* pe, const float* te,
                                const float* g, const float* b, float* out) {
    int s = blockIdx.x;            // one block per token
    int tid = threadIdx.x;         // 256 threads, 3 elems each
    __shared__ float red[256];
    int id = ids[s], t = tt[s];
    float vals[3]; float sum = 0.f;
    #pragma unroll
    for (int r = 0; r < 3; r++) {
        int j = tid + r * 256;
        float x = we[(long)id * kH + j] + pe[(long)s * kH + j] + te[(long)t * kH + j];
        vals[r] = x; sum += x;
    }
    red[tid] = sum; __syncthreads();
    for (int off = 128; off > 0; off >>= 1) { if (tid < off) red[tid] += red[tid + off]; __syncthreads(); }
    float mean = red[0] / kH; __syncthreads();
    float vs = 0.f;
    #pragma unroll
    for (int r = 0; r < 3; r++) { float d = vals[r] - mean; vs += d * d; }
    red[tid] = vs; __syncthreads();
    for (int off = 128; off > 0; off >>= 1) { if (tid < off) red[tid] += red[tid + off]; __syncthreads(); }
    float rstd = rsqrtf(red[0] / kH + 1e-12f);
    #pragma unroll
    for (int r = 0; r < 3; r++) {
        int j = tid + r * 256;
        out[(long)s * kH + j] = (vals[r] - mean) * rstd * g[j] + b[j];
    }
}

// ---------------- LN(res + a) ----------------
__global__ void ln_residual_kernel(const float* a, const float* res,
                                   const float* g, const float* b, float* out) {
    int s = blockIdx.x; int tid = threadIdx.x;
    __shared__ float red[256];
    float vals[3]; float sum = 0.f;
    #pragma unroll
    for (int r = 0; r < 3; r++) {
        int j = tid + r * 256;
        float x = a[(long)s * kH + j] + res[(long)s * kH + j];
        vals[r] = x; sum += x;
    }
    red[tid] = sum; __syncthreads();
    for (int off = 128; off > 0; off >>= 1) { if (tid < off) red[tid] += red[tid + off]; __syncthreads(); }
    float mean = red[0] / kH; __syncthreads();
    float vs = 0.f;
    #pragma unroll
    for (int r = 0; r < 3; r++) { float d = vals[r] - mean; vs += d * d; }
    red[tid] = vs; __syncthreads();
    for (int off = 128; off > 0; off >>= 1) { if (tid < off) red[tid] += red[tid + off]; __syncthreads(); }
    float rstd = rsqrtf(red[0] / kH + 1e-12f);
    #pragma unroll
    for (int r = 0; r < 3; r++) {
        int j = tid + r * 256;
        out[(long)s * kH + j] = (vals[r] - mean) * rstd * g[j] + b[j];
    }
}

// ---------------- generic tiled fp32 GEMM: C[M,N] = A[M,K]@B[K,N] (+bias)(+act) ----------------
// act: 0 = none, 1 = gelu(exact), 2 = relu
__global__ __launch_bounds__(256) void gemm_kernel(const float* __restrict__ A,
                                                   const float* __restrict__ B,
                                                   const float* __restrict__ bias,
                                                   float* __restrict__ C,
                                                   int M, int Nn, int K, int act) {
    __shared__ float As[16][65];
    __shared__ float Bs[16][65];
    int m0 = blockIdx.y * 64, n0 = blockIdx.x * 64;
    int tid = threadIdx.x;
    int tx = tid & 15, ty = tid >> 4;
    float acc[4][4] = {};
    for (int k0 = 0; k0 < K; k0 += 16) {
        #pragma unroll
        for (int r = 0; r < 4; r++) {
            int ii = r * 256 + tid; int m = ii >> 4, kk = ii & 15;
            int gm = m0 + m;
            As[kk][m] = (gm < M) ? A[(long)gm * K + k0 + kk] : 0.f;
        }
        #pragma unroll
        for (int r = 0; r < 4; r++) {
            int ii = r * 256 + tid; int n = ii & 63, kk = ii >> 6;
            int gn = n0 + n;
            Bs[kk][n] = (gn < Nn) ? B[(long)(k0 + kk) * Nn + gn] : 0.f;
        }
        __syncthreads();
        #pragma unroll
        for (int kk = 0; kk < 16; kk++) {
            float a[4], bb[4];
            #pragma unroll
            for (int i = 0; i < 4; i++) a[i] = As[kk][ty * 4 + i];
            #pragma unroll
            for (int j = 0; j < 4; j++) bb[j] = Bs[kk][tx * 4 + j];
            #pragma unroll
            for (int i = 0; i < 4; i++)
                #pragma unroll
                for (int j = 0; j < 4; j++) acc[i][j] += a[i] * bb[j];
        }
        __syncthreads();
    }
    #pragma unroll
    for (int i = 0; i < 4; i++) {
        int gm = m0 + ty * 4 + i; if (gm >= M) continue;
        #pragma unroll
        for (int j = 0; j < 4; j++) {
            int gn = n0 + tx * 4 + j; if (gn >= Nn) continue;
            float vv = acc[i][j] + (bias ? bias[gn] : 0.f);
            if (act == 1) vv = 0.5f * vv * (1.f + erff(vv * 0.70710678118654752f));
            else if (act == 2) vv = fmaxf(vv, 0.f);
            C[(long)gm * Nn + gn] = vv;
        }
    }
}

// ---------------- attention: scores = Q K^T / 8 + maskbias ----------------
__global__ __launch_bounds__(256) void attn_scores_kernel(const float* __restrict__ Q,
                                                          const float* __restrict__ K,
                                                          const float* __restrict__ mb,
                                                          float* __restrict__ scores) {
    int h = blockIdx.z;
    int q0 = blockIdx.y * 64, k0 = blockIdx.x * 64;
    __shared__ float Qs[16][65], Ks[16][65];
    int tid = threadIdx.x; int tx = tid & 15, ty = tid >> 4;
    float acc[4][4] = {};
    for (int d0 = 0; d0 < kDH; d0 += 16) {
        #pragma unroll
        for (int r = 0; r < 4; r++) {
            int ii = r * 256 + tid; int m = ii >> 4, kk = ii & 15;
            Qs[kk][m] = Q[(long)(q0 + m) * kH + h * kDH + d0 + kk];
            Ks[kk][m] = K[(long)(k0 + m) * kH + h * kDH + d0 + kk];
        }
        __syncthreads();
        #pragma unroll
        for (int kk = 0; kk < 16; kk++) {
            float a[4], bb[4];
            #pragma unroll
            for (int i = 0; i < 4; i++) a[i] = Qs[kk][ty * 4 + i];
            #pragma unroll
            for (int j = 0; j < 4; j++) bb[j] = Ks[kk][tx * 4 + j];
            #pragma unroll
            for (int i = 0; i < 4; i++)
                #pragma unroll
                for (int j = 0; j < 4; j++) acc[i][j] += a[i] * bb[j];
        }
        __syncthreads();
    }
    #pragma unroll
    for (int i = 0; i < 4; i++) {
        int qq = q0 + ty * 4 + i;
        #pragma unroll
        for (int j = 0; j < 4; j++) {
            int kkk = k0 + tx * 4 + j;
            scores[((long)h * kS + qq) * kS + kkk] = acc[i][j] * 0.125f + mb[kkk];
        }
    }
}

// ---------------- softmax over rows of 512 ----------------
__global__ void softmax_kernel(float* scores) {
    long row = blockIdx.x;
    float* p = scores + row * kS;
    int tid = threadIdx.x; // 256
    __shared__ float red[256];
    float x0 = p[tid], x1 = p[tid + 256];
    red[tid] = fmaxf(x0, x1); __syncthreads();
    for (int off = 128; off > 0; off >>= 1) { if (tid < off) red[tid] = fmaxf(red[tid], red[tid + off]); __syncthreads(); }
    float mx = red[0]; __syncthreads();
    float e0 = expf(x0 - mx), e1 = expf(x1 - mx);
    red[tid] = e0 + e1; __syncthreads();
    for (int off = 128; off > 0; off >>= 1) { if (tid < off) red[tid] += red[tid + off]; __syncthreads(); }
    float inv = 1.f / red[0];
    p[tid] = e0 * inv; p[tid + 256] = e1 * inv;
}

// ---------------- ctx = P @ V (per head) ----------------
__global__ __launch_bounds__(256) void attn_ctx_kernel(const float* __restrict__ P,
                                                       const float* __restrict__ V,
                                                       float* __restrict__ ctx) {
    int h = blockIdx.y; int q0 = blockIdx.x * 64;
    __shared__ float Ps[16][65], Vs[16][65];
    int tid = threadIdx.x; int tx = tid & 15, ty = tid >> 4;
    float acc[4][4] = {};
    const float* Ph = P + (long)h * kS * kS;
    for (int k0 = 0; k0 < kS; k0 += 16) {
        #pragma unroll
        for (int r = 0; r < 4; r++) {
            int ii = r * 256 + tid; int m = ii >> 4, kk = ii & 15;
            Ps[kk][m] = Ph[(long)(q0 + m) * kS + k0 + kk];
        }
        #pragma unroll
        for (int r = 0; r < 4; r++) {
            int ii = r * 256 + tid; int n = ii & 63, kk = ii >> 6;
            Vs[kk][n] = V[(long)(k0 + kk) * kH + h * kDH + n];
        }
        __syncthreads();
        #pragma unroll
        for (int kk = 0; kk < 16; kk++) {
            float a[4], bb[4];
            #pragma unroll
            for (int i = 0; i < 4; i++) a[i] = Ps[kk][ty * 4 + i];
            #pragma unroll
            for (int j = 0; j < 4; j++) bb[j] = Vs[kk][tx * 4 + j];
            #pragma unroll
            for (int i = 0; i < 4; i++)
                #pragma unroll
                for (int j = 0; j < 4; j++) acc[i][j] += a[i] * bb[j];
        }
        __syncthreads();
    }
    #pragma unroll
    for (int i = 0; i < 4; i++) {
        int qq = q0 + ty * 4 + i;
        #pragma unroll
        for (int j = 0; j < 4; j++) {
            int d = tx * 4 + j;
            ctx[(long)qq * kH + h * kDH + d] = acc[i][j];
        }
    }
}

// ---------------- GCN kernels ----------------
__global__ void maskbias_kernel(const int* mask, float* mb) {
    int i = blockIdx.x * blockDim.x + threadIdx.x;
    if (i < kS) mb[i] = (1.f - (float)mask[i]) * -1e4f;
}

__global__ void deg_kernel(const int* dst, float* deg, int E) {
    int e = blockIdx.x * blockDim.x + threadIdx.x;
    if (e < E) atomicAdd(&deg[dst[e]], 1.f);
}

__global__ void rsqrt_kernel(float* deg, int n) {
    int i = blockIdx.x * blockDim.x + threadIdx.x;
    if (i < n) deg[i] = rsqrtf(deg[i]);   // deg >= 1 always (self-loops)
}

// out[dst] += dinv[src]*dinv[dst]*hw[src]  over all real edges, 128 feats/edge
__global__ void scatter_kernel(const int* __restrict__ src, const int* __restrict__ dst,
                               const float* __restrict__ dinv, const float* __restrict__ hw,
                               float* __restrict__ out, long E) {
    long idx = blockIdx.x * (long)blockDim.x + threadIdx.x;
    if (idx >= E * kGH) return;
    int e = (int)(idx >> 7); int j = (int)(idx & 127);
    int s = src[e], d = dst[e];
    atomicAdd(&out[(long)d * kGH + j], dinv[s] * dinv[d] * hw[(long)s * kGH + j]);
}

// w[src] += norm_e  (source-side total outgoing weight; self-loop added later)
__global__ void edgew_kernel(const int* src, const int* dst, const float* dinv, float* w, int E) {
    int e = blockIdx.x * blockDim.x + threadIdx.x;
    if (e < E) atomicAdd(&w[src[e]], dinv[src[e]] * dinv[dst[e]]);
}

// h = relu(agg + dinv^2*hw (self-loop) + b1)   [in-place on agg ok]
__global__ void gcn_post1_kernel(const float* agg, const float* hw, const float* dinv,
                                 const float* b1, float* h, long n) {
    long i = blockIdx.x * (long)blockDim.x + threadIdx.x;
    if (i >= n) return;
    int u = (int)(i >> 7); int j = (int)(i & 127);
    float di = dinv[u];
    float vv = agg[i] + di * di * hw[i] + b1[j];
    h[i] = fmaxf(vv, 0.f);
}

// s[j] = sum_u (w[u] + dinv[u]^2) * h[u][j]
__global__ void wreduce_kernel(const float* __restrict__ h, const float* __restrict__ w,
                               const float* __restrict__ dinv, float* __restrict__ s, int n) {
    int tid = threadIdx.x; int j = tid & 127; int half = tid >> 7;
    float acc = 0.f;
    for (int u = blockIdx.x * 2 + half; u < n; u += gridDim.x * 2) {
        float di = dinv[u];
        acc += (w[u] + di * di) * h[(long)u * kGH + j];
    }
    __shared__ float red[256];
    red[tid] = acc; __syncthreads();
    if (tid < 128) atomicAdd(&s[j], red[tid] + red[tid + 128]);
}

// g[j2] = (s @ W2)[j2]/N + b2[j2]
__global__ void gcn_final_kernel(const float* s, const float* W2, const float* b2, float* g) {
    int j2 = threadIdx.x; // 128
    float acc = 0.f;
    for (int j = 0; j < kGH; j++) acc += s[j] * W2[(long)j * kGH + j2];
    g[j2] = acc * (1.f / (float)kN) + b2[j2];
}

// ---------------- combine head ----------------
__global__ void combine_kernel(const float* __restrict__ cls, const float* __restrict__ gp,
                               const float* __restrict__ gh, const float* __restrict__ Wc,
                               const float* __restrict__ bc, float* __restrict__ feat) {
    int o = blockIdx.x * blockDim.x + threadIdx.x;
    if (o >= kH) return;
    float acc = 0.f;
    for (int i = 0; i < 768; i++)  acc += cls[i] * Wc[(long)i * kH + o];
    for (int i = 0; i < 128; i++)  acc += gp[i] * Wc[(long)(768 + i) * kH + o];
    for (int i = 0; i < 768; i++)  acc += cls[i] * Wc[(long)(896 + i) * kH + o];
    for (int i = 0; i < 128; i++)  acc += gh[i] * Wc[(long)(1664 + i) * kH + o];
    feat[o] = fmaxf(acc + bc[o], 0.f);
}

__global__ void cls_head_kernel(const float* feat, const float* W, const float* b, float* out) {
    int tid = threadIdx.x; // 256
    float a0 = 0.f, a1 = 0.f, a2 = 0.f;
    for (int o = tid; o < kH; o += 256) {
        float f = feat[o];
        a0 += f * W[o * 3 + 0]; a1 += f * W[o * 3 + 1]; a2 += f * W[o * 3 + 2];
    }
    __shared__ float r0[256], r1[256], r2[256];
    r0[tid] = a0; r1[tid] = a1; r2[tid] = a2; __syncthreads();
    for (int off = 128; off > 0; off >>= 1) {
        if (tid < off) { r0[tid] += r0[tid + off]; r1[tid] += r1[tid + off]; r2[tid] += r2[tid + off]; }
        __syncthreads();
    }
    if (tid == 0) { out[0] = r0[0] + b[0]; out[1] = r1[0] + b[1]; out[2] = r2[0] + b[2]; }
}

// ---------------- launch ----------------
extern "C" void kernel_launch(void* const* d_in, const int* in_sizes, int n_in,
                              void* d_out, int out_size, void* d_ws, size_t ws_size,
                              hipStream_t stream) {
    const int*   input_ids = (const int*)d_in[0];
    const int*   attn_mask = (const int*)d_in[1];
    const int*   type_ids  = (const int*)d_in[2];
    const int*   p_edges   = (const int*)d_in[3];
    const int*   h_edges   = (const int*)d_in[4];
    const float* p_nodes   = (const float*)d_in[5];
    const float* h_nodes   = (const float*)d_in[6];
    const float* word_emb  = (const float*)d_in[7];
    const float* pos_emb   = (const float*)d_in[8];
    const float* type_emb  = (const float*)d_in[9];
    const float* eln_s     = (const float*)d_in[10];
    const float* eln_b     = (const float*)d_in[11];
    const float* Wq = (const float*)d_in[12]; const float* bq = (const float*)d_in[13];
    const float* Wk = (const float*)d_in[14]; const float* bk = (const float*)d_in[15];
    const float* Wv = (const float*)d_in[16]; const float* bv = (const float*)d_in[17];
    const float* Wo = (const float*)d_in[18]; const float* bo = (const float*)d_in[19];
    const float* l1s = (const float*)d_in[20]; const float* l1b = (const float*)d_in[21];
    const float* W1 = (const float*)d_in[22]; const float* b1 = (const float*)d_in[23];
    const float* W2 = (const float*)d_in[24]; const float* b2 = (const float*)d_in[25];
    const float* l2s = (const float*)d_in[26]; const float* l2b = (const float*)d_in[27];
    const float* gW1 = (const float*)d_in[28]; const float* gb1 = (const float*)d_in[29];
    const float* gW2 = (const float*)d_in[30]; const float* gb2 = (const float*)d_in[31];
    const float* cW  = (const float*)d_in[32]; const float* cb  = (const float*)d_in[33];
    const float* clsW = (const float*)d_in[34]; const float* clsB = (const float*)d_in[35];
    float* out = (float*)d_out;

    // workspace layout (floats)
    float* W = (float*)d_ws;
    size_t off = 0;
    auto alloc = [&](size_t n) { float* p = W + off; off += n; return p; };
    float* h    = alloc((size_t)kS * kH);
    float* q    = alloc((size_t)kS * kH);
    float* k    = alloc((size_t)kS * kH);
    float* v    = alloc((size_t)kS * kH);
    float* ctx  = alloc((size_t)kS * kH);
    float* tmp  = alloc((size_t)kS * kH);
    float* h1   = alloc((size_t)kS * kH);
    float* ffn2 = alloc((size_t)kS * kH);
    float* deg  = alloc(kN);
    float* wsum = alloc(kN);
    float* svec = alloc(kGH);
    float* gp   = alloc(kGH);
    float* ghv  = alloc(kGH);
    float* mb   = alloc(kS);
    float* feat = alloc(kH);
    float* big  = W + off;   // reused region: GCN (12.8M floats) / BERT scores+ffn1 (4.72M)
    float* hw1  = big;
    float* agg  = big + (size_t)kN * kGH;
    float* scores = big;
    float* ffn1   = big + (size_t)kNH * kS * kS;

    // ---------- GCN on both graphs (before BERT; shares `big`) ----------
    const int* gsrc[2] = { p_edges, h_edges };
    const int* gdst[2] = { p_edges + kE, h_edges + kE };
    const float* gx[2] = { p_nodes, h_nodes };
    float* gout[2] = { gp, ghv };
    for (int gi = 0; gi < 2; gi++) {
        fill_kernel<<<CDIV((long)kN, 256), 256, 0, stream>>>(deg, 1.f, kN);
        fill_kernel<<<CDIV((long)kN, 256), 256, 0, stream>>>(wsum, 0.f, kN);
        fill_kernel<<<CDIV((long)kN * kGH, 256), 256, 0, stream>>>(agg, 0.f, (long)kN * kGH);
        fill_kernel<<<1, 256, 0, stream>>>(svec, 0.f, kGH);
        deg_kernel<<<CDIV(kE, 256), 256, 0, stream>>>(gdst[gi], deg, kE);
        rsqrt_kernel<<<CDIV(kN, 256), 256, 0, stream>>>(deg, kN);   // deg -> dinv
        // hw1 = x @ gW1  (50000x768 @ 768x128)
        gemm_kernel<<<dim3(CDIV(kGH, 64), CDIV(kN, 64)), 256, 0, stream>>>(
            gx[gi], gW1, nullptr, hw1, kN, kGH, kH, 0);
        scatter_kernel<<<CDIV((long)kE * kGH, 256), 256, 0, stream>>>(
            gsrc[gi], gdst[gi], deg, hw1, agg, kE);
        edgew_kernel<<<CDIV(kE, 256), 256, 0, stream>>>(gsrc[gi], gdst[gi], deg, wsum, kE);
        gcn_post1_kernel<<<CDIV((long)kN * kGH, 256), 256, 0, stream>>>(
            agg, hw1, deg, gb1, agg, (long)kN * kGH);
        wreduce_kernel<<<512, 256, 0, stream>>>(agg, wsum, deg, svec, kN);
        gcn_final_kernel<<<1, kGH, 0, stream>>>(svec, gW2, gb2, gout[gi]);
    }

    // ---------- BERT ----------
    maskbias_kernel<<<2, 256, 0, stream>>>(attn_mask, mb);
    embed_ln_kernel<<<kS, 256, 0, stream>>>(input_ids, type_ids, word_emb, pos_emb, type_emb,
                                            eln_s, eln_b, h);
    for (int l = 0; l < kL; l++) {
        const float* Wq_l = Wq + (size_t)l * kH * kH; const float* bq_l = bq + (size_t)l * kH;
        const float* Wk_l = Wk + (size_t)l * kH * kH; const float* bk_l = bk + (size_t)l * kH;
        const float* Wv_l = Wv + (size_t)l * kH * kH; const float* bv_l = bv + (size_t)l * kH;
        const float* Wo_l = Wo + (size_t)l * kH * kH; const float* bo_l = bo + (size_t)l * kH;
        const float* W1_l = W1 + (size_t)l * kH * kF; const float* b1_l = b1 + (size_t)l * kF;
        const float* W2_l = W2 + (size_t)l * kF * kH; const float* b2_l = b2 + (size_t)l * kH;
        const float* l1s_l = l1s + (size_t)l * kH; const float* l1b_l = l1b + (size_t)l * kH;
        const float* l2s_l = l2s + (size_t)l * kH; const float* l2b_l = l2b + (size_t)l * kH;

        dim3 g88(kH / 64, kS / 64);  // 12 x 8
        gemm_kernel<<<g88, 256, 0, stream>>>(h, Wq_l, bq_l, q, kS, kH, kH, 0);
        gemm_kernel<<<g88, 256, 0, stream>>>(h, Wk_l, bk_l, k, kS, kH, kH, 0);
        gemm_kernel<<<g88, 256, 0, stream>>>(h, Wv_l, bv_l, v, kS, kH, kH, 0);
        attn_scores_kernel<<<dim3(kS / 64, kS / 64, kNH), 256, 0, stream>>>(q, k, mb, scores);
        softmax_kernel<<<kNH * kS, 256, 0, stream>>>(scores);
        attn_ctx_kernel<<<dim3(kS / 64, kNH), 256, 0, stream>>>(scores, v, ctx);
        gemm_kernel<<<g88, 256, 0, stream>>>(ctx, Wo_l, bo_l, tmp, kS, kH, kH, 0);
        ln_residual_kernel<<<kS, 256, 0, stream>>>(tmp, h, l1s_l, l1b_l, h1);
        gemm_kernel<<<dim3(kF / 64, kS / 64), 256, 0, stream>>>(h1, W1_l, b1_l, ffn1, kS, kF, kH, 1);
        gemm_kernel<<<dim3(kH / 64, kS / 64), 256, 0, stream>>>(ffn1, W2_l, b2_l, ffn2, kS, kH, kF, 0);
        ln_residual_kernel<<<kS, 256, 0, stream>>>(ffn2, h1, l2s_l, l2b_l, h);
    }

    // ---------- combine + classifier ----------
    // cls = h row 0
    combine_kernel<<<3, 256, 0, stream>>>(h, gp, ghv, cW, cb, feat);
    cls_head_kernel<<<1, 256, 0, stream>>>(feat, clsW, clsB, out);
}

// Round 2
// 6407.516 us; speedup vs baseline: 2.4354x; 2.4354x over previous
//
#include <hip/hip_runtime.h>
#include <math.h>

// Problem constants
constexpr int kS = 512, kH = 768, kNH = 12, kDH = 64, kF = 3072, kL = 12;
constexpr int kN = 50000, kE = 800000, kGH = 128;

#define CDIV(a,b) (((a)+(b)-1)/(b))

struct Ptr3 { const float* p[3]; };
struct Out3 { float* p[3]; };

// ---------------- generic fill ----------------
__global__ void fill_kernel(float* p, float v, long n) {
    long i = blockIdx.x * (long)blockDim.x + threadIdx.x;
    if (i < n) p[i] = v;
}

// ---------------- embeddings + LN ----------------
__global__ void embed_ln_kernel(const int* ids, const int* tt,
                                const float* we, const float* pe, const float* te,
                                const float* g, const float* b, float* out) {
    int s = blockIdx.x;            // one block per token
    int tid = threadIdx.x;         // 256 threads, 3 elems each
    __shared__ float red[256];
    int id = ids[s], t = tt[s];
    float vals[3]; float sum = 0.f;
    #pragma unroll
    for (int r = 0; r < 3; r++) {
        int j = tid + r * 256;
        float x = we[(long)id * kH + j] + pe[(long)s * kH + j] + te[(long)t * kH + j];
        vals[r] = x; sum += x;
    }
    red[tid] = sum; __syncthreads();
    for (int off = 128; off > 0; off >>= 1) { if (tid < off) red[tid] += red[tid + off]; __syncthreads(); }
    float mean = red[0] / kH; __syncthreads();
    float vs = 0.f;
    #pragma unroll
    for (int r = 0; r < 3; r++) { float d = vals[r] - mean; vs += d * d; }
    red[tid] = vs; __syncthreads();
    for (int off = 128; off > 0; off >>= 1) { if (tid < off) red[tid] += red[tid + off]; __syncthreads(); }
    float rstd = rsqrtf(red[0] / kH + 1e-12f);
    #pragma unroll
    for (int r = 0; r < 3; r++) {
        int j = tid + r * 256;
        out[(long)s * kH + j] = (vals[r] - mean) * rstd * g[j] + b[j];
    }
}

// ---------------- LN(res + a) ----------------
__global__ void ln_residual_kernel(const float* a, const float* res,
                                   const float* g, const float* b, float* out) {
    int s = blockIdx.x; int tid = threadIdx.x;
    __shared__ float red[256];
    float vals[3]; float sum = 0.f;
    #pragma unroll
    for (int r = 0; r < 3; r++) {
        int j = tid + r * 256;
        float x = a[(long)s * kH + j] + res[(long)s * kH + j];
        vals[r] = x; sum += x;
    }
    red[tid] = sum; __syncthreads();
    for (int off = 128; off > 0; off >>= 1) { if (tid < off) red[tid] += red[tid + off]; __syncthreads(); }
    float mean = red[0] / kH; __syncthreads();
    float vs = 0.f;
    #pragma unroll
    for (int r = 0; r < 3; r++) { float d = vals[r] - mean; vs += d * d; }
    red[tid] = vs; __syncthreads();
    for (int off = 128; off > 0; off >>= 1) { if (tid < off) red[tid] += red[tid + off]; __syncthreads(); }
    float rstd = rsqrtf(red[0] / kH + 1e-12f);
    #pragma unroll
    for (int r = 0; r < 3; r++) {
        int j = tid + r * 256;
        out[(long)s * kH + j] = (vals[r] - mean) * rstd * g[j] + b[j];
    }
}

// ---------------- double-buffered 64x64 tile K-chunk MACC loop ----------------
// A is read along K (contiguous); B rows have stride bstride.
// As layout: [buf][k][m] (pad 68), Bs layout: [buf][k][n].
__device__ __forceinline__ void mm_chunk_loop(
    const float* __restrict__ Aptr, bool avalid,
    const float* __restrict__ Bptr, long bstride, int nch,
    float (*As)[16][68], float (*Bs)[16][64],
    int arow, int akq, int brow, int bnq, int tx, int ty, float (&acc)[4][4])
{
    float4 av = avalid ? *(const float4*)Aptr : make_float4(0.f, 0.f, 0.f, 0.f);
    float4 bv = *(const float4*)Bptr;
    As[0][akq + 0][arow] = av.x; As[0][akq + 1][arow] = av.y;
    As[0][akq + 2][arow] = av.z; As[0][akq + 3][arow] = av.w;
    *(float4*)&Bs[0][brow][bnq] = bv;
    for (int c = 0; c < nch; ++c) {
        if (c + 1 < nch) {
            av = avalid ? *(const float4*)(Aptr + (c + 1) * 16) : make_float4(0.f, 0.f, 0.f, 0.f);
            bv = *(const float4*)(Bptr + (long)(c + 1) * 16 * bstride);
        }
        __syncthreads();
        int cb = c & 1;
        #pragma unroll
        for (int kk = 0; kk < 16; ++kk) {
            float4 a = *(const float4*)&As[cb][kk][ty * 4];
            float4 b = *(const float4*)&Bs[cb][kk][tx * 4];
            acc[0][0] += a.x * b.x; acc[0][1] += a.x * b.y; acc[0][2] += a.x * b.z; acc[0][3] += a.x * b.w;
            acc[1][0] += a.y * b.x; acc[1][1] += a.y * b.y; acc[1][2] += a.y * b.z; acc[1][3] += a.y * b.w;
            acc[2][0] += a.z * b.x; acc[2][1] += a.z * b.y; acc[2][2] += a.z * b.z; acc[2][3] += a.z * b.w;
            acc[3][0] += a.w * b.x; acc[3][1] += a.w * b.y; acc[3][2] += a.w * b.z; acc[3][3] += a.w * b.w;
        }
        if (c + 1 < nch) {
            int nb = cb ^ 1;
            As[nb][akq + 0][arow] = av.x; As[nb][akq + 1][arow] = av.y;
            As[nb][akq + 2][arow] = av.z; As[nb][akq + 3][arow] = av.w;
            *(float4*)&Bs[nb][brow][bnq] = bv;
        }
    }
}

// ---------------- split-K GEMM: C[M,N] = A[M,K] @ B[K,N] ----------------
// gridDim.z = nW * S; w = z/S selects weight variant (fused QKV), s = z%S the K-chunk.
// If Cdirect != nullptr (requires S==1, nW==1): write C directly with bias/act.
// Else: write partials part[(w*S+s)*M*N + ...]; bias/act applied in epilogue.
__global__ __launch_bounds__(256) void gemm_sk_kernel(
    const float* __restrict__ A, Ptr3 Bp, float* __restrict__ part,
    float* __restrict__ Cdirect, const float* __restrict__ biasD,
    int M, int Nn, int K, int S, int act)
{
    __shared__ float As[2][16][68];
    __shared__ float Bs[2][16][64];
    int w = blockIdx.z / S, s = blockIdx.z % S;
    const float* B = Bp.p[w];
    int Kc = K / S;                 // all uses: K, Kc multiples of 16
    int kbeg = s * Kc;
    int m0 = blockIdx.y * 64, n0 = blockIdx.x * 64;
    int tid = threadIdx.x;
    int tx = tid & 15, ty = tid >> 4;
    int arow = tid >> 2, akq = (tid & 3) * 4;
    int brow = tid >> 4, bnq = (tid & 15) * 4;
    int gma = m0 + arow;
    bool avalid = gma < M;
    const float* Aptr = A + (long)gma * K + kbeg + akq;
    const float* Bptr = B + (long)(kbeg + brow) * Nn + n0 + bnq;
    float acc[4][4] = {};
    mm_chunk_loop(Aptr, avalid, Bptr, Nn, Kc / 16, As, Bs, arow, akq, brow, bnq, tx, ty, acc);
    if (Cdirect) {
        #pragma unroll
        for (int i = 0; i < 4; i++) {
            int gm = m0 + ty * 4 + i; if (gm >= M) continue;
            float4 vv;
            float bx = biasD ? biasD[n0 + tx * 4 + 0] : 0.f;
            float by = biasD ? biasD[n0 + tx * 4 + 1] : 0.f;
            float bz = biasD ? biasD[n0 + tx * 4 + 2] : 0.f;
            float bw = biasD ? biasD[n0 + tx * 4 + 3] : 0.f;
            vv.x = acc[i][0] + bx; vv.y = acc[i][1] + by; vv.z = acc[i][2] + bz; vv.w = acc[i][3] + bw;
            if (act == 1) {
                vv.x = 0.5f * vv.x * (1.f + erff(vv.x * 0.70710678118654752f));
                vv.y = 0.5f * vv.y * (1.f + erff(vv.y * 0.70710678118654752f));
                vv.z = 0.5f * vv.z * (1.f + erff(vv.z * 0.70710678118654752f));
                vv.w = 0.5f * vv.w * (1.f + erff(vv.w * 0.70710678118654752f));
            } else if (act == 2) {
                vv.x = fmaxf(vv.x, 0.f); vv.y = fmaxf(vv.y, 0.f);
                vv.z = fmaxf(vv.z, 0.f); vv.w = fmaxf(vv.w, 0.f);
            }
            *(float4*)&Cdirect[(long)gm * Nn + n0 + tx * 4] = vv;
        }
    } else {
        long MN = (long)M * Nn;
        float* Pp = part + (long)(w * S + s) * MN;
        #pragma unroll
        for (int i = 0; i < 4; i++) {
            int gm = m0 + ty * 4 + i; if (gm >= M) continue;
            float4 vv; vv.x = acc[i][0]; vv.y = acc[i][1]; vv.z = acc[i][2]; vv.w = acc[i][3];
            *(float4*)&Pp[(long)gm * Nn + n0 + tx * 4] = vv;
        }
    }
}

// ---------------- split-K epilogue: out = act(sum_s part + bias) ----------------
__global__ void splitk_epi_kernel(const float* __restrict__ part, Ptr3 bias, Out3 outp,
                                  long MN, int Nn, int S, int act) {
    int w = blockIdx.y;
    long i = ((long)blockIdx.x * blockDim.x + threadIdx.x) * 4;
    if (i >= MN) return;
    const float* P = part + (long)w * S * MN + i;
    float4 a = *(const float4*)P;
    for (int s2 = 1; s2 < S; ++s2) {
        float4 b = *(const float4*)(P + (long)s2 * MN);
        a.x += b.x; a.y += b.y; a.z += b.z; a.w += b.w;
    }
    const float* bw = bias.p[w];
    if (bw) {
        int n = (int)(i % Nn);
        a.x += bw[n]; a.y += bw[n + 1]; a.z += bw[n + 2]; a.w += bw[n + 3];
    }
    if (act == 1) {
        a.x = 0.5f * a.x * (1.f + erff(a.x * 0.70710678118654752f));
        a.y = 0.5f * a.y * (1.f + erff(a.y * 0.70710678118654752f));
        a.z = 0.5f * a.z * (1.f + erff(a.z * 0.70710678118654752f));
        a.w = 0.5f * a.w * (1.f + erff(a.w * 0.70710678118654752f));
    } else if (act == 2) {
        a.x = fmaxf(a.x, 0.f); a.y = fmaxf(a.y, 0.f); a.z = fmaxf(a.z, 0.f); a.w = fmaxf(a.w, 0.f);
    }
    *(float4*)(outp.p[w] + i) = a;
}

// ---------------- attention: scores = Q K^T / 8 + maskbias ----------------
__global__ __launch_bounds__(256) void attn_scores_kernel(const float* __restrict__ Q,
                                                          const float* __restrict__ K,
                                                          const float* __restrict__ mb,
                                                          float* __restrict__ scores) {
    int h = blockIdx.z;
    int q0 = blockIdx.y * 64, k0 = blockIdx.x * 64;
    __shared__ float Qs[16][65], Ks[16][65];
    int tid = threadIdx.x; int tx = tid & 15, ty = tid >> 4;
    float acc[4][4] = {};
    for (int d0 = 0; d0 < kDH; d0 += 16) {
        #pragma unroll
        for (int r = 0; r < 4; r++) {
            int ii = r * 256 + tid; int m = ii >> 4, kk = ii & 15;
            Qs[kk][m] = Q[(long)(q0 + m) * kH + h * kDH + d0 + kk];
            Ks[kk][m] = K[(long)(k0 + m) * kH + h * kDH + d0 + kk];
        }
        __syncthreads();
        #pragma unroll
        for (int kk = 0; kk < 16; kk++) {
            float a[4], bb[4];
            #pragma unroll
            for (int i = 0; i < 4; i++) a[i] = Qs[kk][ty * 4 + i];
            #pragma unroll
            for (int j = 0; j < 4; j++) bb[j] = Ks[kk][tx * 4 + j];
            #pragma unroll
            for (int i = 0; i < 4; i++)
                #pragma unroll
                for (int j = 0; j < 4; j++) acc[i][j] += a[i] * bb[j];
        }
        __syncthreads();
    }
    #pragma unroll
    for (int i = 0; i < 4; i++) {
        int qq = q0 + ty * 4 + i;
        #pragma unroll
        for (int j = 0; j < 4; j++) {
            int kkk = k0 + tx * 4 + j;
            scores[((long)h * kS + qq) * kS + kkk] = acc[i][j] * 0.125f + mb[kkk];
        }
    }
}

// ---------------- softmax over rows of 512 ----------------
__global__ void softmax_kernel(float* scores) {
    long row = blockIdx.x;
    float* p = scores + row * kS;
    int tid = threadIdx.x; // 256
    __shared__ float red[256];
    float x0 = p[tid], x1 = p[tid + 256];
    red[tid] = fmaxf(x0, x1); __syncthreads();
    for (int off = 128; off > 0; off >>= 1) { if (tid < off) red[tid] = fmaxf(red[tid], red[tid + off]); __syncthreads(); }
    float mx = red[0]; __syncthreads();
    float e0 = expf(x0 - mx), e1 = expf(x1 - mx);
    red[tid] = e0 + e1; __syncthreads();
    for (int off = 128; off > 0; off >>= 1) { if (tid < off) red[tid] += red[tid + off]; __syncthreads(); }
    float inv = 1.f / red[0];
    p[tid] = e0 * inv; p[tid + 256] = e1 * inv;
}

// ---------------- ctx partial = P @ V over K-chunk (4-way split), per head ----------------
// part layout: [s][m][kH] with head h occupying columns h*64..h*64+63
__global__ __launch_bounds__(256) void attn_ctx_split_kernel(const float* __restrict__ P,
                                                             const float* __restrict__ V,
                                                             float* __restrict__ part) {
    __shared__ float As[2][16][68];
    __shared__ float Bs[2][16][64];
    int q0 = blockIdx.x * 64;
    int h = blockIdx.y >> 2, s = blockIdx.y & 3;
    int tid = threadIdx.x;
    int tx = tid & 15, ty = tid >> 4;
    int arow = tid >> 2, akq = (tid & 3) * 4;
    int brow = tid >> 4, bnq = (tid & 15) * 4;
    int kbeg = s * 128;
    const float* Aptr = P + ((long)h * kS + q0 + arow) * kS + kbeg + akq;
    const float* Bptr = V + (long)(kbeg + brow) * kH + h * kDH + bnq;
    float acc[4][4] = {};
    mm_chunk_loop(Aptr, true, Bptr, kH, 128 / 16, As, Bs, arow, akq, brow, bnq, tx, ty, acc);
    float* Pp = part + (long)s * kS * kH + (long)(q0 + ty * 4) * kH + h * kDH + tx * 4;
    #pragma unroll
    for (int i = 0; i < 4; i++) {
        float4 vv; vv.x = acc[i][0]; vv.y = acc[i][1]; vv.z = acc[i][2]; vv.w = acc[i][3];
        *(float4*)(Pp + (long)i * kH) = vv;
    }
}

// ---------------- GCN kernels ----------------
__global__ void maskbias_kernel(const int* mask, float* mb) {
    int i = blockIdx.x * blockDim.x + threadIdx.x;
    if (i < kS) mb[i] = (1.f - (float)mask[i]) * -1e4f;
}

__global__ void deg_kernel(const int* dst, float* deg, int E) {
    int e = blockIdx.x * blockDim.x + threadIdx.x;
    if (e < E) atomicAdd(&deg[dst[e]], 1.f);
}

__global__ void rsqrt_kernel(float* deg, int n) {
    int i = blockIdx.x * blockDim.x + threadIdx.x;
    if (i < n) deg[i] = rsqrtf(deg[i]);   // deg >= 1 always (self-loops)
}

// out[dst] += dinv[src]*dinv[dst]*hw[src], float4 per thread (32 thr/edge)
__global__ void scatter_kernel(const int* __restrict__ src, const int* __restrict__ dst,
                               const float* __restrict__ dinv, const float* __restrict__ hw,
                               float* __restrict__ out, long E) {
    long idx = blockIdx.x * (long)blockDim.x + threadIdx.x;
    if (idx >= E * 32) return;
    int e = (int)(idx >> 5); int j4 = (int)(idx & 31) * 4;
    int s = src[e], d = dst[e];
    float c = dinv[s] * dinv[d];
    float4 hv = *(const float4*)&hw[(long)s * kGH + j4];
    float* o = &out[(long)d * kGH + j4];
    atomicAdd(o + 0, c * hv.x);
    atomicAdd(o + 1, c * hv.y);
    atomicAdd(o + 2, c * hv.z);
    atomicAdd(o + 3, c * hv.w);
}

// w[src] += norm_e  (source-side total outgoing weight; self-loop added later)
__global__ void edgew_kernel(const int* src, const int* dst, const float* dinv, float* w, int E) {
    int e = blockIdx.x * blockDim.x + threadIdx.x;
    if (e < E) atomicAdd(&w[src[e]], dinv[src[e]] * dinv[dst[e]]);
}

// h = relu(agg + dinv^2*hw (self-loop) + b1)   [in-place on agg ok]
__global__ void gcn_post1_kernel(const float* agg, const float* hw, const float* dinv,
                                 const float* b1, float* h, long n) {
    long i = blockIdx.x * (long)blockDim.x + threadIdx.x;
    if (i >= n) return;
    int u = (int)(i >> 7); int j = (int)(i & 127);
    float di = dinv[u];
    float vv = agg[i] + di * di * hw[i] + b1[j];
    h[i] = fmaxf(vv, 0.f);
}

// s[j] = sum_u (w[u] + dinv[u]^2) * h[u][j]
__global__ void wreduce_kernel(const float* __restrict__ h, const float* __restrict__ w,
                               const float* __restrict__ dinv, float* __restrict__ s, int n) {
    int tid = threadIdx.x; int j = tid & 127; int half = tid >> 7;
    float acc = 0.f;
    for (int u = blockIdx.x * 2 + half; u < n; u += gridDim.x * 2) {
        float di = dinv[u];
        acc += (w[u] + di * di) * h[(long)u * kGH + j];
    }
    __shared__ float red[256];
    red[tid] = acc; __syncthreads();
    if (tid < 128) atomicAdd(&s[j], red[tid] + red[tid + 128]);
}

// g[j2] = (s @ W2)[j2]/N + b2[j2]
__global__ void gcn_final_kernel(const float* s, const float* W2, const float* b2, float* g) {
    int j2 = threadIdx.x; // 128
    float acc = 0.f;
    for (int j = 0; j < kGH; j++) acc += s[j] * W2[(long)j * kGH + j2];
    g[j2] = acc * (1.f / (float)kN) + b2[j2];
}

// ---------------- combine head ----------------
__global__ void combine_kernel(const float* __restrict__ cls, const float* __restrict__ gp,
                               const float* __restrict__ gh, const float* __restrict__ Wc,
                               const float* __restrict__ bc, float* __restrict__ feat) {
    int o = blockIdx.x * blockDim.x + threadIdx.x;
    if (o >= kH) return;
    float acc = 0.f;
    for (int i = 0; i < 768; i++)  acc += cls[i] * Wc[(long)i * kH + o];
    for (int i = 0; i < 128; i++)  acc += gp[i] * Wc[(long)(768 + i) * kH + o];
    for (int i = 0; i < 768; i++)  acc += cls[i] * Wc[(long)(896 + i) * kH + o];
    for (int i = 0; i < 128; i++)  acc += gh[i] * Wc[(long)(1664 + i) * kH + o];
    feat[o] = fmaxf(acc + bc[o], 0.f);
}

__global__ void cls_head_kernel(const float* feat, const float* W, const float* b, float* out) {
    int tid = threadIdx.x; // 256
    float a0 = 0.f, a1 = 0.f, a2 = 0.f;
    for (int o = tid; o < kH; o += 256) {
        float f = feat[o];
        a0 += f * W[o * 3 + 0]; a1 += f * W[o * 3 + 1]; a2 += f * W[o * 3 + 2];
    }
    __shared__ float r0[256], r1[256], r2[256];
    r0[tid] = a0; r1[tid] = a1; r2[tid] = a2; __syncthreads();
    for (int off = 128; off > 0; off >>= 1) {
        if (tid < off) { r0[tid] += r0[tid + off]; r1[tid] += r1[tid + off]; r2[tid] += r2[tid + off]; }
        __syncthreads();
    }
    if (tid == 0) { out[0] = r0[0] + b[0]; out[1] = r1[0] + b[1]; out[2] = r2[0] + b[2]; }
}

// ---------------- launch ----------------
extern "C" void kernel_launch(void* const* d_in, const int* in_sizes, int n_in,
                              void* d_out, int out_size, void* d_ws, size_t ws_size,
                              hipStream_t stream) {
    const int*   input_ids = (const int*)d_in[0];
    const int*   attn_mask = (const int*)d_in[1];
    const int*   type_ids  = (const int*)d_in[2];
    const int*   p_edges   = (const int*)d_in[3];
    const int*   h_edges   = (const int*)d_in[4];
    const float* p_nodes   = (const float*)d_in[5];
    const float* h_nodes   = (const float*)d_in[6];
    const float* word_emb  = (const float*)d_in[7];
    const float* pos_emb   = (const float*)d_in[8];
    const float* type_emb  = (const float*)d_in[9];
    const float* eln_s     = (const float*)d_in[10];
    const float* eln_b     = (const float*)d_in[11];
    const float* Wq = (const float*)d_in[12]; const float* bq = (const float*)d_in[13];
    const float* Wk = (const float*)d_in[14]; const float* bk = (const float*)d_in[15];
    const float* Wv = (const float*)d_in[16]; const float* bv = (const float*)d_in[17];
    const float* Wo = (const float*)d_in[18]; const float* bo = (const float*)d_in[19];
    const float* l1s = (const float*)d_in[20]; const float* l1b = (const float*)d_in[21];
    const float* W1 = (const float*)d_in[22]; const float* b1 = (const float*)d_in[23];
    const float* W2 = (const float*)d_in[24]; const float* b2 = (const float*)d_in[25];
    const float* l2s = (const float*)d_in[26]; const float* l2b = (const float*)d_in[27];
    const float* gW1 = (const float*)d_in[28]; const float* gb1 = (const float*)d_in[29];
    const float* gW2 = (const float*)d_in[30]; const float* gb2 = (const float*)d_in[31];
    const float* cW  = (const float*)d_in[32]; const float* cb  = (const float*)d_in[33];
    const float* clsW = (const float*)d_in[34]; const float* clsB = (const float*)d_in[35];
    float* out = (float*)d_out;

    // workspace layout (floats)
    float* W = (float*)d_ws;
    size_t off = 0;
    auto alloc = [&](size_t n) { float* p = W + off; off += n; return p; };
    float* h    = alloc((size_t)kS * kH);
    float* q    = alloc((size_t)kS * kH);
    float* k    = alloc((size_t)kS * kH);
    float* v    = alloc((size_t)kS * kH);
    float* ctx  = alloc((size_t)kS * kH);
    float* tmp  = alloc((size_t)kS * kH);
    float* h1   = alloc((size_t)kS * kH);
    float* ffn2 = alloc((size_t)kS * kH);
    float* deg  = alloc(kN);
    float* wsum = alloc(kN);
    float* svec = alloc(kGH);
    float* gp   = alloc(kGH);
    float* ghv  = alloc(kGH);
    float* mb   = alloc(kS);
    float* feat = alloc(kH);
    float* big  = W + off;   // reused region, 12.8M floats (GCN) / scores+ffn1+part (BERT)
    // GCN phase:
    float* hw1  = big;
    float* agg  = big + (size_t)kN * kGH;
    // BERT phase (all within the 12.8M-float big region):
    float* scores = big;                                        // 3.146M floats
    float* ffn1   = big + (size_t)kNH * kS * kS;                // 1.573M floats
    float* part   = ffn1 + (size_t)kS * kF;                     // up to 3.146M floats

    const long MN_H = (long)kS * kH;   // 393216
    const long MN_F = (long)kS * kF;   // 1572864

    // ---------- GCN on both graphs (before BERT; shares `big`) ----------
    const int* gsrc[2] = { p_edges, h_edges };
    const int* gdst[2] = { p_edges + kE, h_edges + kE };
    const float* gx[2] = { p_nodes, h_nodes };
    float* gout[2] = { gp, ghv };
    for (int gi = 0; gi < 2; gi++) {
        fill_kernel<<<CDIV((long)kN, 256), 256, 0, stream>>>(deg, 1.f, kN);
        fill_kernel<<<CDIV((long)kN, 256), 256, 0, stream>>>(wsum, 0.f, kN);
        fill_kernel<<<CDIV((long)kN * kGH, 256), 256, 0, stream>>>(agg, 0.f, (long)kN * kGH);
        fill_kernel<<<1, 256, 0, stream>>>(svec, 0.f, kGH);
        deg_kernel<<<CDIV(kE, 256), 256, 0, stream>>>(gdst[gi], deg, kE);
        rsqrt_kernel<<<CDIV(kN, 256), 256, 0, stream>>>(deg, kN);   // deg -> dinv
        // hw1 = x @ gW1  (50000x768 @ 768x128), direct write path
        gemm_sk_kernel<<<dim3(kGH / 64, CDIV(kN, 64), 1), 256, 0, stream>>>(
            gx[gi], Ptr3{{gW1, nullptr, nullptr}}, nullptr, hw1, nullptr, kN, kGH, kH, 1, 0);
        scatter_kernel<<<CDIV((long)kE * 32, 256), 256, 0, stream>>>(
            gsrc[gi], gdst[gi], deg, hw1, agg, kE);
        edgew_kernel<<<CDIV(kE, 256), 256, 0, stream>>>(gsrc[gi], gdst[gi], deg, wsum, kE);
        gcn_post1_kernel<<<CDIV((long)kN * kGH, 256), 256, 0, stream>>>(
            agg, hw1, deg, gb1, agg, (long)kN * kGH);
        wreduce_kernel<<<512, 256, 0, stream>>>(agg, wsum, deg, svec, kN);
        gcn_final_kernel<<<1, kGH, 0, stream>>>(svec, gW2, gb2, gout[gi]);
    }

    // ---------- BERT ----------
    maskbias_kernel<<<2, 256, 0, stream>>>(attn_mask, mb);
    embed_ln_kernel<<<kS, 256, 0, stream>>>(input_ids, type_ids, word_emb, pos_emb, type_emb,
                                            eln_s, eln_b, h);
    for (int l = 0; l < kL; l++) {
        const float* Wq_l = Wq + (size_t)l * kH * kH; const float* bq_l = bq + (size_t)l * kH;
        const float* Wk_l = Wk + (size_t)l * kH * kH; const float* bk_l = bk + (size_t)l * kH;
        const float* Wv_l = Wv + (size_t)l * kH * kH; const float* bv_l = bv + (size_t)l * kH;
        const float* Wo_l = Wo + (size_t)l * kH * kH; const float* bo_l = bo + (size_t)l * kH;
        const float* W1_l = W1 + (size_t)l * kH * kF; const float* b1_l = b1 + (size_t)l * kF;
        const float* W2_l = W2 + (size_t)l * kF * kH; const float* b2_l = b2 + (size_t)l * kH;
        const float* l1s_l = l1s + (size_t)l * kH; const float* l1b_l = l1b + (size_t)l * kH;
        const float* l2s_l = l2s + (size_t)l * kH; const float* l2b_l = l2b + (size_t)l * kH;

        // QKV fused: nW=3, S=2 -> 576 blocks
        gemm_sk_kernel<<<dim3(kH / 64, kS / 64, 6), 256, 0, stream>>>(
            h, Ptr3{{Wq_l, Wk_l, Wv_l}}, part, nullptr, nullptr, kS, kH, kH, 2, 0);
        splitk_epi_kernel<<<dim3((int)(MN_H / 4 / 256), 3), 256, 0, stream>>>(
            part, Ptr3{{bq_l, bk_l, bv_l}}, Out3{{q, k, v}}, MN_H, kH, 2, 0);
        attn_scores_kernel<<<dim3(kS / 64, kS / 64, kNH), 256, 0, stream>>>(q, k, mb, scores);
        softmax_kernel<<<kNH * kS, 256, 0, stream>>>(scores);
        // ctx: K-split 4 -> 384 blocks, deterministic partial + epilogue
        attn_ctx_split_kernel<<<dim3(kS / 64, kNH * 4), 256, 0, stream>>>(scores, v, part);
        splitk_epi_kernel<<<dim3((int)(MN_H / 4 / 256), 1), 256, 0, stream>>>(
            part, Ptr3{{nullptr, nullptr, nullptr}}, Out3{{ctx, nullptr, nullptr}}, MN_H, kH, 4, 0);
        // Wo: S=4 -> 384 blocks
        gemm_sk_kernel<<<dim3(kH / 64, kS / 64, 4), 256, 0, stream>>>(
            ctx, Ptr3{{Wo_l, nullptr, nullptr}}, part, nullptr, nullptr, kS, kH, kH, 4, 0);
        splitk_epi_kernel<<<dim3((int)(MN_H / 4 / 256), 1), 256, 0, stream>>>(
            part, Ptr3{{bo_l, nullptr, nullptr}}, Out3{{tmp, nullptr, nullptr}}, MN_H, kH, 4, 0);
        ln_residual_kernel<<<kS, 256, 0, stream>>>(tmp, h, l1s_l, l1b_l, h1);
        // FFN1: S=2 -> 768 blocks, gelu in epilogue
        gemm_sk_kernel<<<dim3(kF / 64, kS / 64, 2), 256, 0, stream>>>(
            h1, Ptr3{{W1_l, nullptr, nullptr}}, part, nullptr, nullptr, kS, kF, kH, 2, 0);
        splitk_epi_kernel<<<dim3((int)(MN_F / 4 / 256), 1), 256, 0, stream>>>(
            part, Ptr3{{b1_l, nullptr, nullptr}}, Out3{{ffn1, nullptr, nullptr}}, MN_F, kF, 2, 1);
        // FFN2: S=8 -> 768 blocks
        gemm_sk_kernel<<<dim3(kH / 64, kS / 64, 8), 256, 0, stream>>>(
            ffn1, Ptr3{{W2_l, nullptr, nullptr}}, part, nullptr, nullptr, kS, kH, kF, 8, 0);
        splitk_epi_kernel<<<dim3((int)(MN_H / 4 / 256), 1), 256, 0, stream>>>(
            part, Ptr3{{b2_l, nullptr, nullptr}}, Out3{{ffn2, nullptr, nullptr}}, MN_H, kH, 8, 0);
        ln_residual_kernel<<<kS, 256, 0, stream>>>(ffn2, h1, l2s_l, l2b_l, h);
    }

    // ---------- combine + classifier ----------
    combine_kernel<<<3, 256, 0, stream>>>(h, gp, ghv, cW, cb, feat);
    cls_head_kernel<<<1, 256, 0, stream>>>(feat, clsW, clsB, out);
}